// Round 2
// baseline (262.010 us; speedup 1.0000x reference)
//
#include <hip/hip_runtime.h>
#include <hip/hip_bf16.h>
#include <hip/hip_fp16.h>

// RecursiveNN forest bottom-up pass, fp32 in / fp32 out.
// Single fused kernel for levels 1..8: level 1 streams 134 MB of leaves through
// LDS staging into an LDS-resident Hbuf (128 rows = one quarter-tree frontier),
// then levels 2..8 halve in place. No H1 HBM round-trip, no prep kernel:
// W/P fragments are converted fp32->fp16 in-kernel (L2-served, hidden under
// the first leaf loads). Projection is a 4-step chained fp16 MFMA.
// K3: top 2 levels (3 nodes/tree) in fp32 (verified).

typedef _Float16 f16_t;
typedef _Float16 f16x4 __attribute__((ext_vector_type(4)));
typedef _Float16 f16x8 __attribute__((ext_vector_type(8)));
typedef float f32x4 __attribute__((ext_vector_type(4)));

#define HSTRIDE 136   // f16 elems per row slot: 272 B, 16B-aligned

static __device__ __forceinline__ f32x4 mfma16(f16x8 a, f16x8 b, f32x4 c) {
    return __builtin_amdgcn_mfma_f32_16x16x32_f16(a, b, c, 0, 0, 0);
}

static __device__ __forceinline__ f16x8 cvt8(const float* p) {
    const float4 a = *(const float4*)p;
    const float4 b = *(const float4*)(p + 4);
    f16x8 t = { (f16_t)a.x, (f16_t)a.y, (f16_t)a.z, (f16_t)a.w,
                (f16_t)b.x, (f16_t)b.y, (f16_t)b.z, (f16_t)b.w };
    return t;
}

// ---------------- fused K1+K2: levels 1..8 for one 128-row quarter-tree ----------------
__global__ __launch_bounds__(256, 3)
void forest_kernel(const float* __restrict__ leaves,
                   const float* __restrict__ W,
                   const float* __restrict__ P,
                   const float* __restrict__ bW,
                   const float* __restrict__ bP,
                   f16_t* __restrict__ Q,          // [1024,128] quarter roots
                   float* __restrict__ out)
{
    __shared__ f16_t Stg[2][32 * HSTRIDE];       // 17408 B leaf staging dbuf
    __shared__ f16_t Hbuf[128 * HSTRIDE];        // 34816 B frontier, in-place halving

    const int tid   = threadIdx.x;
    const int wave  = tid >> 6;
    const int lane  = tid & 63;
    const int mlane = lane & 15;
    const int q     = lane >> 4;
    const int tree  = blockIdx.x >> 2;
    const int qq    = blockIdx.x & 3;
    const size_t m0 = (size_t)blockIdx.x * 128;  // global level-1 pair-row base
    const float* leafbase = leaves + (size_t)blockIdx.x * 32768;

    auto store_stage = [&](int buf, const float4* pf) {
        #pragma unroll
        for (int r = 0; r < 4; ++r) {
            const int idx = tid + r * 256;       // 1024 float4 chunks = 32 leaf rows
            const int row = idx >> 5;
            const int c4  = idx & 31;
            f16x4 t4 = { (f16_t)pf[r].x, (f16_t)pf[r].y, (f16_t)pf[r].z, (f16_t)pf[r].w };
            *(f16x4*)&Stg[buf][row * HSTRIDE + c4 * 4] = t4;
        }
    };

    // issue first leaf chunk ASAP; W/P fragment conversion hides under it
    float4 pf[4];
    #pragma unroll
    for (int r = 0; r < 4; ++r) pf[r] = ((const float4*)leafbase)[tid + r * 256];

    // W b-frags (gemm_bt, verified): lane holds W[col][k*32 + q*8 + e], fp32->fp16
    f16x8 wh[2][8];
    float bwv[2];
    #pragma unroll
    for (int n = 0; n < 2; ++n) {
        const int col = wave * 32 + n * 16 + mlane;
        bwv[n] = bW[col];
        #pragma unroll
        for (int k = 0; k < 8; ++k)
            wh[n][k] = cvt8(&W[col * 256 + k * 32 + q * 8]);
    }

    // P b-frags, N padded 5->16 (zero rows for mlane>=5)
    f16x8 pb[4] = {};
    if (mlane < 5) {
        #pragma unroll
        for (int kb = 0; kb < 4; ++kb)
            pb[kb] = cvt8(&P[mlane * 128 + kb * 32 + q * 8]);
    }
    const float bpv = (mlane < 5) ? bP[mlane] : 0.f;

    store_stage(0, pf);

    // proj of Hbuf rows [hrow0, hrow0+16) via 4 chained MFMAs; wave 0 calls this.
    auto proj_store = [&](int hrow0, size_t orow0, int valid) {
        f32x4 pc = {};
        #pragma unroll
        for (int kb = 0; kb < 4; ++kb) {
            const f16x8 ha = *(const f16x8*)&Hbuf[(hrow0 + mlane) * HSTRIDE + kb * 32 + q * 8];
            pc = mfma16(ha, pb[kb], pc);
        }
        if (mlane < 5) {
            #pragma unroll
            for (int r = 0; r < 4; ++r) {
                const int row = q * 4 + r;       // D layout: row=q*4+r, col=mlane (verified)
                if (row < valid) out[(orow0 + row) * 5 + mlane] = pc[r] + bpv;
            }
        }
    };

    // ---- phase 1: level 1, 8 chunks of 16 pair-rows; H -> Hbuf (LDS) ----
    for (int c = 0; c < 8; ++c) {
        __syncthreads();                         // Stg[c&1] visible
        if (c < 7) {
            #pragma unroll
            for (int r = 0; r < 4; ++r)
                pf[r] = ((const float4*)leafbase)[(c + 1) * 1024 + tid + r * 256];
        }
        // A-frags from pair-rows (verified pattern)
        f16x8 af[8];
        const f16_t* sb = Stg[c & 1];
        #pragma unroll
        for (int k = 0; k < 8; ++k) {
            const int off  = k * 64 + q * 16;    // byte offset in 512B pair-row
            const int trow = off >> 8;
            const int ce   = (off & 255) >> 1;
            af[k] = *(const f16x8*)&sb[(2 * mlane + trow) * HSTRIDE + ce];
        }
        f32x4 acc0 = {}, acc1 = {};
        #pragma unroll
        for (int k = 0; k < 8; ++k) {
            acc0 = mfma16(af[k], wh[0][k], acc0);
            acc1 = mfma16(af[k], wh[1][k], acc1);
        }
        if (c < 7) store_stage((c + 1) & 1, pf);

        // bias + relu -> Hbuf rows [c*16, c*16+16)  (C-layout: col=lane&15, row=q*4+r)
        #pragma unroll
        for (int r = 0; r < 4; ++r) {
            float v0 = fmaxf(acc0[r] + bwv[0], 0.f);
            float v1 = fmaxf(acc1[r] + bwv[1], 0.f);
            Hbuf[(c * 16 + q * 4 + r) * HSTRIDE + wave * 32 + mlane]      = (f16_t)v0;
            Hbuf[(c * 16 + q * 4 + r) * HSTRIDE + wave * 32 + 16 + mlane] = (f16_t)v1;
        }
        __syncthreads();                         // Hbuf chunk complete

        if (wave == 0) proj_store(c * 16, m0 + c * 16, 16);
        // next-chunk writes go to rows (c+1)*16 — disjoint from proj reads; the
        // loop-top barrier orders Stg staging behind this wave's proj anyway.
    }

    // ---- phase 2: levels 2..8, in-place LDS halving (verified structure) ----
    int Mprev = 128;
    #pragma unroll 1
    for (int j = 2; j <= 8; ++j) {
        const int Mnew   = Mprev >> 1;
        const int chunks = (Mnew + 15) >> 4;
        const size_t off_j = 256 * (1024 - (2048 >> j));
        for (int c = 0; c < chunks; ++c) {
            f16x8 af[8];
            #pragma unroll
            for (int k = 0; k < 8; ++k) {
                const int off  = k * 64 + q * 16;
                const int trow = off >> 8;
                const int ce   = (off & 255) >> 1;
                af[k] = *(const f16x8*)&Hbuf[(32 * c + 2 * mlane + trow) * HSTRIDE + ce];
            }
            __syncthreads();                     // all reads done before writes
            f32x4 acc0 = {}, acc1 = {};
            #pragma unroll
            for (int k = 0; k < 8; ++k) {
                acc0 = mfma16(af[k], wh[0][k], acc0);
                acc1 = mfma16(af[k], wh[1][k], acc1);
            }
            #pragma unroll
            for (int r = 0; r < 4; ++r) {
                float v0 = fmaxf(acc0[r] + bwv[0], 0.f);
                float v1 = fmaxf(acc1[r] + bwv[1], 0.f);
                Hbuf[(c * 16 + q * 4 + r) * HSTRIDE + wave * 32 + mlane]      = (f16_t)v0;
                Hbuf[(c * 16 + q * 4 + r) * HSTRIDE + wave * 32 + 16 + mlane] = (f16_t)v1;
            }
            __syncthreads();                     // writes visible for proj / next reads

            const int valid = (Mnew - c * 16 < 16) ? (Mnew - c * 16) : 16;
            if (wave == 0)
                proj_store(c * 16,
                           off_j + (size_t)tree * (Mnew * 4) + (size_t)qq * Mnew + c * 16,
                           valid);
        }
        Mprev = Mnew;
    }

    if (tid < 16)
        *(uint4*)&Q[(size_t)blockIdx.x * 128 + tid * 8] = *(const uint4*)&Hbuf[tid * 8];
}

// ---------------- K3: top 2 levels, fp32 (verified) ----------------
__global__ __launch_bounds__(128, 4)
void rnn_top_kernel(const f16_t* __restrict__ Q,
                    const float* __restrict__ W,
                    const float* __restrict__ bW,
                    const float* __restrict__ P,
                    const float* __restrict__ bP,
                    float* __restrict__ out)
{
    __shared__ float qs[512];
    __shared__ float hs[384];
    const int t    = threadIdx.x;
    const int tree = blockIdx.x;

    #pragma unroll
    for (int i = 0; i < 4; ++i)
        qs[t + i * 128] = (float)Q[(size_t)tree * 512 + t + i * 128];
    __syncthreads();

    const float* wr = W + t * 256;
    float s0 = bW[t], s1 = s0;
    for (int k = 0; k < 256; k += 4) {
        const float4 wv = *(const float4*)(wr + k);
        s0 += wv.x * qs[k]     + wv.y * qs[k + 1]     + wv.z * qs[k + 2]     + wv.w * qs[k + 3];
        s1 += wv.x * qs[256+k] + wv.y * qs[256+k + 1] + wv.z * qs[256+k + 2] + wv.w * qs[256+k + 3];
    }
    hs[t]       = fmaxf(s0, 0.f);
    hs[128 + t] = fmaxf(s1, 0.f);
    __syncthreads();

    float s2 = bW[t];
    for (int k = 0; k < 256; k += 4) {
        const float4 wv = *(const float4*)(wr + k);
        s2 += wv.x * hs[k] + wv.y * hs[k + 1] + wv.z * hs[k + 2] + wv.w * hs[k + 3];
    }
    hs[256 + t] = fmaxf(s2, 0.f);
    __syncthreads();

    if (t < 15) {
        const int node = t / 5, c = t % 5;
        float s = bP[c];
        for (int k = 0; k < 128; ++k) s += hs[node * 128 + k] * P[c * 128 + k];
        const size_t row = (node < 2) ? (261120 + (size_t)tree * 2 + node)
                                      : (261632 + (size_t)tree);
        out[row * 5 + c] = s;
    }
}

extern "C" void kernel_launch(void* const* d_in, const int* in_sizes, int n_in,
                              void* d_out, int out_size, void* d_ws, size_t ws_size,
                              hipStream_t stream) {
    const float* leaves = (const float*)d_in[0];   // [256,1024,128] fp32
    const float* W      = (const float*)d_in[1];   // [128,256] fp32
    const float* bW     = (const float*)d_in[2];   // [128] fp32
    const float* P      = (const float*)d_in[3];   // [5,128] fp32
    const float* bP     = (const float*)d_in[4];   // [5] fp32
    float* out = (float*)d_out;                    // [256*1023, 5] fp32

    // ws layout (f16 elems): Q 131072 only (~256 KB)
    f16_t* Q = (f16_t*)d_ws;

    forest_kernel<<<dim3(1024), dim3(256), 0, stream>>>(leaves, W, P, bW, bP, Q, out);
    rnn_top_kernel<<<dim3(256), dim3(128), 0, stream>>>(Q, W, bW, P, bP, out);
}

// Round 3
// 248.002 us; speedup vs baseline: 1.0565x; 1.0565x over previous
//
#include <hip/hip_runtime.h>
#include <hip/hip_bf16.h>
#include <hip/hip_fp16.h>

// RecursiveNN forest bottom-up pass, fp32 in / fp32 out.
// forest_kernel: one block per EIGHTH-tree (64 level-1 pair-rows). Level 1
// streams leaves through a double-buffered LDS stage into an LDS-resident
// Hbuf, then levels 2..7 halve in place. Grid 2048, LDS 34.8 KB -> 3-4
// blocks/CU resident (latency hiding; round-2 counters showed 2 blocks/CU
// and all pipes <12% busy). launch_bounds(256,2): (256,3) forced VGPR=84
// and spilled wh/pb fragments to scratch (+13 us, WRITE_SIZE +5 MB).
// rnn_top_kernel: top 3 levels (8 eighth-roots -> 7 nodes/tree) in fp32.

typedef _Float16 f16_t;
typedef _Float16 f16x4 __attribute__((ext_vector_type(4)));
typedef _Float16 f16x8 __attribute__((ext_vector_type(8)));
typedef float f32x4 __attribute__((ext_vector_type(4)));

#define HSTRIDE 136   // f16 elems per row slot: 272 B, 16B-aligned

static __device__ __forceinline__ f32x4 mfma16(f16x8 a, f16x8 b, f32x4 c) {
    return __builtin_amdgcn_mfma_f32_16x16x32_f16(a, b, c, 0, 0, 0);
}

static __device__ __forceinline__ f16x8 cvt8(const float* p) {
    const float4 a = *(const float4*)p;
    const float4 b = *(const float4*)(p + 4);
    f16x8 t = { (f16_t)a.x, (f16_t)a.y, (f16_t)a.z, (f16_t)a.w,
                (f16_t)b.x, (f16_t)b.y, (f16_t)b.z, (f16_t)b.w };
    return t;
}

// ---------------- fused levels 1..7 for one 64-pair-row eighth-tree ----------------
__global__ __launch_bounds__(256, 2)
void forest_kernel(const float* __restrict__ leaves,
                   const float* __restrict__ W,
                   const float* __restrict__ P,
                   const float* __restrict__ bW,
                   const float* __restrict__ bP,
                   f16_t* __restrict__ Q,          // [2048,128] eighth-roots
                   float* __restrict__ out)
{
    __shared__ f16_t Stg[2][32 * HSTRIDE];       // 17408 B leaf staging dbuf
    __shared__ f16_t Hbuf[64 * HSTRIDE];         // 17408 B frontier, in-place halving

    const int tid   = threadIdx.x;
    const int wave  = tid >> 6;
    const int lane  = tid & 63;
    const int mlane = lane & 15;
    const int q     = lane >> 4;
    const int tree  = blockIdx.x >> 3;
    const int e     = blockIdx.x & 7;
    const size_t m0 = (size_t)blockIdx.x * 64;   // global level-1 pair-row base
    const float* leafbase = leaves + (size_t)blockIdx.x * 16384;

    auto store_stage = [&](int buf, const float4* pf) {
        #pragma unroll
        for (int r = 0; r < 4; ++r) {
            const int idx = tid + r * 256;       // 1024 float4 chunks = 32 leaf rows
            const int row = idx >> 5;
            const int c4  = idx & 31;
            f16x4 t4 = { (f16_t)pf[r].x, (f16_t)pf[r].y, (f16_t)pf[r].z, (f16_t)pf[r].w };
            *(f16x4*)&Stg[buf][row * HSTRIDE + c4 * 4] = t4;
        }
    };

    // issue first leaf chunk ASAP; W/P fragment conversion hides under it
    float4 pf[4];
    #pragma unroll
    for (int r = 0; r < 4; ++r) pf[r] = ((const float4*)leafbase)[tid + r * 256];

    // W b-frags (gemm_bt, verified): lane holds W[col][k*32 + q*8 + e], fp32->fp16
    f16x8 wh[2][8];
    float bwv[2];
    #pragma unroll
    for (int n = 0; n < 2; ++n) {
        const int col = wave * 32 + n * 16 + mlane;
        bwv[n] = bW[col];
        #pragma unroll
        for (int k = 0; k < 8; ++k)
            wh[n][k] = cvt8(&W[col * 256 + k * 32 + q * 8]);
    }

    // P b-frags, N padded 5->16 (zero rows for mlane>=5)
    f16x8 pb[4] = {};
    if (mlane < 5) {
        #pragma unroll
        for (int kb = 0; kb < 4; ++kb)
            pb[kb] = cvt8(&P[mlane * 128 + kb * 32 + q * 8]);
    }
    const float bpv = (mlane < 5) ? bP[mlane] : 0.f;

    store_stage(0, pf);

    // proj of Hbuf rows [hrow0, hrow0+16) via 4 chained MFMAs; wave 0 calls this.
    auto proj_store = [&](int hrow0, size_t orow0, int valid) {
        f32x4 pc = {};
        #pragma unroll
        for (int kb = 0; kb < 4; ++kb) {
            const f16x8 ha = *(const f16x8*)&Hbuf[(hrow0 + mlane) * HSTRIDE + kb * 32 + q * 8];
            pc = mfma16(ha, pb[kb], pc);
        }
        if (mlane < 5) {
            #pragma unroll
            for (int r = 0; r < 4; ++r) {
                const int row = q * 4 + r;       // D layout: row=q*4+r, col=mlane (verified)
                if (row < valid) out[(orow0 + row) * 5 + mlane] = pc[r] + bpv;
            }
        }
    };

    // ---- phase 1: level 1, 4 chunks of 16 pair-rows; H -> Hbuf (LDS) ----
    for (int c = 0; c < 4; ++c) {
        __syncthreads();                         // Stg[c&1] visible
        if (c < 3) {
            #pragma unroll
            for (int r = 0; r < 4; ++r)
                pf[r] = ((const float4*)leafbase)[(c + 1) * 1024 + tid + r * 256];
        }
        // A-frags from pair-rows (verified pattern)
        f16x8 af[8];
        const f16_t* sb = Stg[c & 1];
        #pragma unroll
        for (int k = 0; k < 8; ++k) {
            const int off  = k * 64 + q * 16;    // byte offset in 512B pair-row
            const int trow = off >> 8;
            const int ce   = (off & 255) >> 1;
            af[k] = *(const f16x8*)&sb[(2 * mlane + trow) * HSTRIDE + ce];
        }
        f32x4 acc0 = {}, acc1 = {};
        #pragma unroll
        for (int k = 0; k < 8; ++k) {
            acc0 = mfma16(af[k], wh[0][k], acc0);
            acc1 = mfma16(af[k], wh[1][k], acc1);
        }
        if (c < 3) store_stage((c + 1) & 1, pf);

        // bias + relu -> Hbuf rows [c*16, c*16+16)  (C-layout: col=lane&15, row=q*4+r)
        #pragma unroll
        for (int r = 0; r < 4; ++r) {
            float v0 = fmaxf(acc0[r] + bwv[0], 0.f);
            float v1 = fmaxf(acc1[r] + bwv[1], 0.f);
            Hbuf[(c * 16 + q * 4 + r) * HSTRIDE + wave * 32 + mlane]      = (f16_t)v0;
            Hbuf[(c * 16 + q * 4 + r) * HSTRIDE + wave * 32 + 16 + mlane] = (f16_t)v1;
        }
        __syncthreads();                         // Hbuf chunk complete

        if (wave == 0) proj_store(c * 16, m0 + c * 16, 16);
        // next-chunk writes go to rows (c+1)*16 — disjoint from proj reads; the
        // loop-top barrier orders Stg staging behind this wave's proj anyway.
    }

    // ---- phase 2: levels 2..7, in-place LDS halving (verified structure) ----
    int Mprev = 64;
    #pragma unroll 1
    for (int j = 2; j <= 7; ++j) {
        const int Mnew   = Mprev >> 1;
        const int chunks = (Mnew + 15) >> 4;
        const size_t off_j = 256 * (1024 - (2048 >> j));
        const size_t base_j = off_j + (size_t)tree * (1024 >> j) + (size_t)e * (128 >> j);
        for (int c = 0; c < chunks; ++c) {
            f16x8 af[8];
            #pragma unroll
            for (int k = 0; k < 8; ++k) {
                const int off  = k * 64 + q * 16;
                const int trow = off >> 8;
                const int ce   = (off & 255) >> 1;
                af[k] = *(const f16x8*)&Hbuf[(32 * c + 2 * mlane + trow) * HSTRIDE + ce];
            }
            __syncthreads();                     // all reads done before writes
            f32x4 acc0 = {}, acc1 = {};
            #pragma unroll
            for (int k = 0; k < 8; ++k) {
                acc0 = mfma16(af[k], wh[0][k], acc0);
                acc1 = mfma16(af[k], wh[1][k], acc1);
            }
            #pragma unroll
            for (int r = 0; r < 4; ++r) {
                float v0 = fmaxf(acc0[r] + bwv[0], 0.f);
                float v1 = fmaxf(acc1[r] + bwv[1], 0.f);
                Hbuf[(c * 16 + q * 4 + r) * HSTRIDE + wave * 32 + mlane]      = (f16_t)v0;
                Hbuf[(c * 16 + q * 4 + r) * HSTRIDE + wave * 32 + 16 + mlane] = (f16_t)v1;
            }
            __syncthreads();                     // writes visible for proj / next reads

            const int valid = (Mnew - c * 16 < 16) ? (Mnew - c * 16) : 16;
            if (wave == 0)
                proj_store(c * 16, base_j + c * 16, valid);
        }
        Mprev = Mnew;
    }

    if (tid < 16)
        *(uint4*)&Q[(size_t)blockIdx.x * 128 + tid * 8] = *(const uint4*)&Hbuf[tid * 8];
}

// ---------------- top 3 levels (8 eighth-roots -> 4 -> 2 -> 1), fp32 ----------------
__global__ __launch_bounds__(128, 4)
void rnn_top_kernel(const f16_t* __restrict__ Q,
                    const float* __restrict__ W,
                    const float* __restrict__ bW,
                    const float* __restrict__ P,
                    const float* __restrict__ bP,
                    float* __restrict__ out)
{
    __shared__ float qs[1024];
    __shared__ float hs[896];    // [0,512): level-8 nodes, [512,768): level-9, [768,896): root
    const int t    = threadIdx.x;
    const int tree = blockIdx.x;

    #pragma unroll
    for (int i = 0; i < 8; ++i)
        qs[t + i * 128] = (float)Q[(size_t)tree * 1024 + t + i * 128];
    __syncthreads();

    const float* wr = W + t * 256;

    // level 8: 4 nodes from 8 eighth-roots
    float s8[4];
    #pragma unroll
    for (int n = 0; n < 4; ++n) s8[n] = bW[t];
    for (int k = 0; k < 256; k += 4) {
        const float4 wv = *(const float4*)(wr + k);
        #pragma unroll
        for (int n = 0; n < 4; ++n) {
            const float* qb = qs + n * 256 + k;
            s8[n] += wv.x * qb[0] + wv.y * qb[1] + wv.z * qb[2] + wv.w * qb[3];
        }
    }
    #pragma unroll
    for (int n = 0; n < 4; ++n) hs[n * 128 + t] = fmaxf(s8[n], 0.f);
    __syncthreads();

    // level 9: 2 nodes
    float s9[2];
    s9[0] = s9[1] = bW[t];
    for (int k = 0; k < 256; k += 4) {
        const float4 wv = *(const float4*)(wr + k);
        #pragma unroll
        for (int m = 0; m < 2; ++m) {
            const float* hb = hs + m * 256 + k;
            s9[m] += wv.x * hb[0] + wv.y * hb[1] + wv.z * hb[2] + wv.w * hb[3];
        }
    }
    hs[512 + t] = fmaxf(s9[0], 0.f);
    hs[640 + t] = fmaxf(s9[1], 0.f);
    __syncthreads();

    // level 10: root
    float s10 = bW[t];
    for (int k = 0; k < 256; k += 4) {
        const float4 wv = *(const float4*)(wr + k);
        const float* hb = hs + 512 + k;
        s10 += wv.x * hb[0] + wv.y * hb[1] + wv.z * hb[2] + wv.w * hb[3];
    }
    hs[768 + t] = fmaxf(s10, 0.f);
    __syncthreads();

    // projections: 7 nodes x 5 classes
    if (t < 35) {
        const int node = t / 5, c = t % 5;
        float s = bP[c];
        const float* hb = hs + node * 128;
        for (int k = 0; k < 128; ++k) s += hb[k] * P[c * 128 + k];
        size_t row;
        if (node < 4)      row = 260096 + (size_t)tree * 4 + node;        // level 8 (n=4/tree)
        else if (node < 6) row = 261120 + (size_t)tree * 2 + (node - 4);  // level 9 (n=2/tree)
        else               row = 261632 + (size_t)tree;                   // level 10 root
        out[row * 5 + c] = s;
    }
}

extern "C" void kernel_launch(void* const* d_in, const int* in_sizes, int n_in,
                              void* d_out, int out_size, void* d_ws, size_t ws_size,
                              hipStream_t stream) {
    const float* leaves = (const float*)d_in[0];   // [256,1024,128] fp32
    const float* W      = (const float*)d_in[1];   // [128,256] fp32
    const float* bW     = (const float*)d_in[2];   // [128] fp32
    const float* P      = (const float*)d_in[3];   // [5,128] fp32
    const float* bP     = (const float*)d_in[4];   // [5] fp32
    float* out = (float*)d_out;                    // [256*1023, 5] fp32

    // ws layout (f16 elems): Q 262144 (512 KB)
    f16_t* Q = (f16_t*)d_ws;

    forest_kernel<<<dim3(2048), dim3(256), 0, stream>>>(leaves, W, P, bW, bP, Q, out);
    rnn_top_kernel<<<dim3(256), dim3(128), 0, stream>>>(Q, W, bW, P, bP, out);
}

// Round 4
// 226.627 us; speedup vs baseline: 1.1561x; 1.0943x over previous
//
#include <hip/hip_runtime.h>
#include <hip/hip_bf16.h>
#include <hip/hip_fp16.h>

// RecursiveNN forest bottom-up pass, fp32 in / fp32 out.
// forest_kernel: one block per EIGHTH-tree (64 level-1 pair-rows).
// Round-3 counters: 88 us with all pipes <13%, ~1.2 KB/CU avg in flight
// (Little's law) -> barrier-drain bound: every chunk-step's __syncthreads
// emitted s_waitcnt vmcnt(0), draining prefetch loads + proj stores (~5k cyc).
// This version removes ALL global ops from the barrier path:
//   - whole-block leaf preload (64 KB -> f16 LDS arena) before any barrier
//   - phase 1 (level 1, 4 chunks): ZERO barriers (per-wave column slices)
//   - level-1 proj deferred, split across 4 waves (one store-drain total)
//   - phase 2 (levels 2..7): lgkm-only barriers; proj -> LDS outbox,
//     flushed coalesced at kernel end
// LDS 53504 B -> 3 blocks/CU. prep converts W/P to f16 once (2048 blocks
// shouldn't each re-read 128 KB fp32 W).
// rnn_top_kernel: top 3 levels (8 eighth-roots -> 7 nodes/tree) fp32, verified.

typedef _Float16 f16_t;
typedef _Float16 f16x4 __attribute__((ext_vector_type(4)));
typedef _Float16 f16x8 __attribute__((ext_vector_type(8)));
typedef float f32x4 __attribute__((ext_vector_type(4)));

#define HSTRIDE 136   // f16 elems per row slot: 272 B, 16B-aligned

static __device__ __forceinline__ f32x4 mfma16(f16x8 a, f16x8 b, f32x4 c) {
    return __builtin_amdgcn_mfma_f32_16x16x32_f16(a, b, c, 0, 0, 0);
}

// One-shot: W [128,256] fp32 -> fp16 Wh; P [5,128] fp32 -> fp16 Ph.
__global__ void prep_kernel(const float* __restrict__ W, const float* __restrict__ P,
                            f16_t* __restrict__ Wh, f16_t* __restrict__ Ph) {
    if (blockIdx.x < 128) {
        const int i = blockIdx.x * 256 + threadIdx.x;
        Wh[i] = (f16_t)W[i];
    } else {
        for (int i = threadIdx.x; i < 640; i += 256) Ph[i] = (f16_t)P[i];
    }
}

// ---------------- fused levels 1..7 for one 64-pair-row eighth-tree ----------------
__global__ __launch_bounds__(256, 2)
void forest_kernel(const float* __restrict__ leaves,
                   const f16_t* __restrict__ Wh,
                   const f16_t* __restrict__ Ph,
                   const float* __restrict__ bW,
                   const float* __restrict__ bP,
                   f16_t* __restrict__ Q,          // [2048,128] eighth-roots
                   float* __restrict__ out)
{
    __shared__ f16_t Arena[128 * HSTRIDE];       // 34816 B: all leaf rows, f16
    __shared__ f16_t Hbuf[64 * HSTRIDE];         // 17408 B frontier, in-place halving
    __shared__ float OutB[320];                  // 1280 B proj outbox (levels 2..7)

    const int tid   = threadIdx.x;
    const int wave  = tid >> 6;
    const int lane  = tid & 63;
    const int mlane = lane & 15;
    const int q     = lane >> 4;
    const int tree  = blockIdx.x >> 3;
    const int e     = blockIdx.x & 7;
    const size_t m0 = (size_t)blockIdx.x * 64;   // global level-1 pair-row base
    const float* leafbase = leaves + (size_t)blockIdx.x * 16384;

    // W b-frags (gemm_bt, verified): lane holds W[col][k*32 + q*8 + e]
    f16x8 wh[2][8];
    float bwv[2];
    #pragma unroll
    for (int n = 0; n < 2; ++n) {
        const int col = wave * 32 + n * 16 + mlane;
        bwv[n] = bW[col];
        #pragma unroll
        for (int k = 0; k < 8; ++k)
            wh[n][k] = *(const f16x8*)&Wh[col * 256 + k * 32 + q * 8];
    }

    // P b-frags, N padded 5->16 (zero rows for mlane>=5)
    f16x8 pb[4] = {};
    if (mlane < 5) {
        #pragma unroll
        for (int kb = 0; kb < 4; ++kb)
            pb[kb] = *(const f16x8*)&Ph[mlane * 128 + kb * 32 + q * 8];
    }
    const float bpv = (mlane < 5) ? bP[mlane] : 0.f;

    // ---- whole-block leaf preload: 64 KB fp32 -> f16 arena, 2 batches ----
    #pragma unroll
    for (int b = 0; b < 2; ++b) {
        float4 t[8];
        #pragma unroll
        for (int r = 0; r < 8; ++r)
            t[r] = ((const float4*)leafbase)[tid + (b * 8 + r) * 256];
        #pragma unroll
        for (int r = 0; r < 8; ++r) {
            const int idx = tid + (b * 8 + r) * 256;   // 4096 float4 = 128 leaf rows
            const int row = idx >> 5;
            const int c4  = idx & 31;
            f16x4 t4 = { (f16_t)t[r].x, (f16_t)t[r].y, (f16_t)t[r].z, (f16_t)t[r].w };
            *(f16x4*)&Arena[row * HSTRIDE + c4 * 4] = t4;
        }
    }
    __syncthreads();                             // arena visible to all waves

    // ---- phase 1: level 1, 4 chunks, NO barriers (per-wave col slices) ----
    #pragma unroll
    for (int c = 0; c < 4; ++c) {
        f16x8 af[8];
        #pragma unroll
        for (int k = 0; k < 8; ++k) {
            const int off  = k * 64 + q * 16;    // byte offset in 512B pair-row
            const int trow = off >> 8;
            const int ce   = (off & 255) >> 1;
            af[k] = *(const f16x8*)&Arena[(32 * c + 2 * mlane + trow) * HSTRIDE + ce];
        }
        f32x4 acc0 = {}, acc1 = {};
        #pragma unroll
        for (int k = 0; k < 8; ++k) {
            acc0 = mfma16(af[k], wh[0][k], acc0);
            acc1 = mfma16(af[k], wh[1][k], acc1);
        }
        #pragma unroll
        for (int r = 0; r < 4; ++r) {
            float v0 = fmaxf(acc0[r] + bwv[0], 0.f);
            float v1 = fmaxf(acc1[r] + bwv[1], 0.f);
            Hbuf[(c * 16 + q * 4 + r) * HSTRIDE + wave * 32 + mlane]      = (f16_t)v0;
            Hbuf[(c * 16 + q * 4 + r) * HSTRIDE + wave * 32 + 16 + mlane] = (f16_t)v1;
        }
    }
    __syncthreads();                             // Hbuf rows 0..63 complete

    // ---- level-1 proj: each wave projects its own 16 rows, direct to out ----
    {
        const int hrow0 = wave * 16;
        f32x4 pc = {};
        #pragma unroll
        for (int kb = 0; kb < 4; ++kb) {
            const f16x8 ha = *(const f16x8*)&Hbuf[(hrow0 + mlane) * HSTRIDE + kb * 32 + q * 8];
            pc = mfma16(ha, pb[kb], pc);
        }
        if (mlane < 5) {
            #pragma unroll
            for (int r = 0; r < 4; ++r) {
                const int row = q * 4 + r;       // D layout: row=q*4+r, col=mlane (verified)
                out[(m0 + hrow0 + row) * 5 + mlane] = pc[r] + bpv;
            }
        }
    }

    // ---- phase 2: levels 2..7, in-place LDS halving; proj -> outbox ----
    int Mprev = 64;
    #pragma unroll 1
    for (int j = 2; j <= 7; ++j) {
        const int Mnew   = Mprev >> 1;
        const int chunks = (Mnew + 15) >> 4;
        const int obase  = 64 - (256 >> j);      // outbox row base for level j
        for (int c = 0; c < chunks; ++c) {
            f16x8 af[8];
            #pragma unroll
            for (int k = 0; k < 8; ++k) {
                const int off  = k * 64 + q * 16;
                const int trow = off >> 8;
                const int ce   = (off & 255) >> 1;
                af[k] = *(const f16x8*)&Hbuf[(32 * c + 2 * mlane + trow) * HSTRIDE + ce];
            }
            __syncthreads();                     // all reads done before writes
            f32x4 acc0 = {}, acc1 = {};
            #pragma unroll
            for (int k = 0; k < 8; ++k) {
                acc0 = mfma16(af[k], wh[0][k], acc0);
                acc1 = mfma16(af[k], wh[1][k], acc1);
            }
            #pragma unroll
            for (int r = 0; r < 4; ++r) {
                float v0 = fmaxf(acc0[r] + bwv[0], 0.f);
                float v1 = fmaxf(acc1[r] + bwv[1], 0.f);
                Hbuf[(c * 16 + q * 4 + r) * HSTRIDE + wave * 32 + mlane]      = (f16_t)v0;
                Hbuf[(c * 16 + q * 4 + r) * HSTRIDE + wave * 32 + 16 + mlane] = (f16_t)v1;
            }
            __syncthreads();                     // writes visible

            const int valid = (Mnew - c * 16 < 16) ? (Mnew - c * 16) : 16;
            if (wave == 0) {                     // proj -> LDS outbox (no global ops)
                f32x4 pc = {};
                #pragma unroll
                for (int kb = 0; kb < 4; ++kb) {
                    const f16x8 ha = *(const f16x8*)&Hbuf[(c * 16 + mlane) * HSTRIDE + kb * 32 + q * 8];
                    pc = mfma16(ha, pb[kb], pc);
                }
                if (mlane < 5) {
                    #pragma unroll
                    for (int r = 0; r < 4; ++r) {
                        const int row = q * 4 + r;
                        if (row < valid)
                            OutB[(obase + c * 16 + row) * 5 + mlane] = pc[r] + bpv;
                    }
                }
            }
        }
        Mprev = Mnew;
    }
    __syncthreads();                             // outbox + Hbuf row 0 final

    // ---- flush outbox: 63 rows x 5, coalesced-ish ----
    for (int t2 = tid; t2 < 315; t2 += 256) {
        const int lrow = t2 / 5;
        const int cls  = t2 - lrow * 5;
        int j, i;
        if      (lrow < 32) { j = 2; i = lrow;      }
        else if (lrow < 48) { j = 3; i = lrow - 32; }
        else if (lrow < 56) { j = 4; i = lrow - 48; }
        else if (lrow < 60) { j = 5; i = lrow - 56; }
        else if (lrow < 62) { j = 6; i = lrow - 60; }
        else                { j = 7; i = 0;         }
        const size_t grow = (size_t)256 * (1024 - (2048 >> j))
                          + (size_t)tree * (1024 >> j) + (size_t)e * (128 >> j) + i;
        out[grow * 5 + cls] = OutB[t2];
    }

    if (tid < 16)
        *(uint4*)&Q[(size_t)blockIdx.x * 128 + tid * 8] = *(const uint4*)&Hbuf[tid * 8];
}

// ---------------- top 3 levels (8 eighth-roots -> 4 -> 2 -> 1), fp32 ----------------
__global__ __launch_bounds__(128, 4)
void rnn_top_kernel(const f16_t* __restrict__ Q,
                    const float* __restrict__ W,
                    const float* __restrict__ bW,
                    const float* __restrict__ P,
                    const float* __restrict__ bP,
                    float* __restrict__ out)
{
    __shared__ float qs[1024];
    __shared__ float hs[896];    // [0,512): level-8 nodes, [512,768): level-9, [768,896): root
    const int t    = threadIdx.x;
    const int tree = blockIdx.x;

    #pragma unroll
    for (int i = 0; i < 8; ++i)
        qs[t + i * 128] = (float)Q[(size_t)tree * 1024 + t + i * 128];
    __syncthreads();

    const float* wr = W + t * 256;

    // level 8: 4 nodes from 8 eighth-roots
    float s8[4];
    #pragma unroll
    for (int n = 0; n < 4; ++n) s8[n] = bW[t];
    for (int k = 0; k < 256; k += 4) {
        const float4 wv = *(const float4*)(wr + k);
        #pragma unroll
        for (int n = 0; n < 4; ++n) {
            const float* qb = qs + n * 256 + k;
            s8[n] += wv.x * qb[0] + wv.y * qb[1] + wv.z * qb[2] + wv.w * qb[3];
        }
    }
    #pragma unroll
    for (int n = 0; n < 4; ++n) hs[n * 128 + t] = fmaxf(s8[n], 0.f);
    __syncthreads();

    // level 9: 2 nodes
    float s9[2];
    s9[0] = s9[1] = bW[t];
    for (int k = 0; k < 256; k += 4) {
        const float4 wv = *(const float4*)(wr + k);
        #pragma unroll
        for (int m = 0; m < 2; ++m) {
            const float* hb = hs + m * 256 + k;
            s9[m] += wv.x * hb[0] + wv.y * hb[1] + wv.z * hb[2] + wv.w * hb[3];
        }
    }
    hs[512 + t] = fmaxf(s9[0], 0.f);
    hs[640 + t] = fmaxf(s9[1], 0.f);
    __syncthreads();

    // level 10: root
    float s10 = bW[t];
    for (int k = 0; k < 256; k += 4) {
        const float4 wv = *(const float4*)(wr + k);
        const float* hb = hs + 512 + k;
        s10 += wv.x * hb[0] + wv.y * hb[1] + wv.z * hb[2] + wv.w * hb[3];
    }
    hs[768 + t] = fmaxf(s10, 0.f);
    __syncthreads();

    // projections: 7 nodes x 5 classes
    if (t < 35) {
        const int node = t / 5, c = t % 5;
        float s = bP[c];
        const float* hb = hs + node * 128;
        for (int k = 0; k < 128; ++k) s += hb[k] * P[c * 128 + k];
        size_t row;
        if (node < 4)      row = 260096 + (size_t)tree * 4 + node;        // level 8 (n=4/tree)
        else if (node < 6) row = 261120 + (size_t)tree * 2 + (node - 4);  // level 9 (n=2/tree)
        else               row = 261632 + (size_t)tree;                   // level 10 root
        out[row * 5 + c] = s;
    }
}

extern "C" void kernel_launch(void* const* d_in, const int* in_sizes, int n_in,
                              void* d_out, int out_size, void* d_ws, size_t ws_size,
                              hipStream_t stream) {
    const float* leaves = (const float*)d_in[0];   // [256,1024,128] fp32
    const float* W      = (const float*)d_in[1];   // [128,256] fp32
    const float* bW     = (const float*)d_in[2];   // [128] fp32
    const float* P      = (const float*)d_in[3];   // [5,128] fp32
    const float* bP     = (const float*)d_in[4];   // [5] fp32
    float* out = (float*)d_out;                    // [256*1023, 5] fp32

    // ws layout (f16 elems): Wh 32768 | Ph 1024 | Q 262144  (~592 KB)
    f16_t* Wh = (f16_t*)d_ws;
    f16_t* Ph = Wh + 32768;
    f16_t* Q  = Wh + 32768 + 1024;

    prep_kernel<<<dim3(129), dim3(256), 0, stream>>>(W, P, Wh, Ph);
    forest_kernel<<<dim3(2048), dim3(256), 0, stream>>>(leaves, Wh, Ph, bW, bP, Q, out);
    rnn_top_kernel<<<dim3(256), dim3(128), 0, stream>>>(Q, W, bW, P, bP, out);
}